// Round 1
// baseline (238.575 us; speedup 1.0000x reference)
//
#include <hip/hip_runtime.h>

// InvRT: out[m,n,b,l] = -(e0 + e1*tanh((z - e2)*e3)), params from eta_fault[Mask[m,l]]
// Shapes: z (8, 64, 512, 128) f32; eta_fault (19,4) f32; Mask (8,128) int.
// Pure streaming elementwise op -> HBM-bound (~43us floor at 6.3 TB/s).

#define M_DIM 8
#define L_DIM 128
#define NB 32768            // N*B = 64*512
#define PER_M 4194304       // N*B*L floats per m
#define BLOCKS_PER_M 256
#define THREADS 256
#define PER_BLOCK 16384     // PER_M / BLOCKS_PER_M
#define ITERS 16            // PER_BLOCK / (THREADS*4)

__device__ __forceinline__ float fast_tanh(float x) {
    // tanh(x) = 1 - 2/(1 + exp(2x)); exp(2x) = exp2(x * 2*log2(e))
    // Saturates correctly: exp2->inf => rcp->0 => +1; exp2->0 => 1-2 = -1.
    float t = __builtin_amdgcn_exp2f(x * 2.8853900817779268f);
    float r = __builtin_amdgcn_rcpf(1.0f + t);
    return __builtin_fmaf(-2.0f, r, 1.0f);
}

__global__ __launch_bounds__(THREADS) void invrt_kernel(
    const float* __restrict__ z,
    const float* __restrict__ eta_fault,
    const int*  __restrict__ mask,
    float* __restrict__ out)
{
    const int tid   = threadIdx.x;
    const int bid   = blockIdx.x;
    const int m     = bid >> 8;       // 256 blocks per m
    const int chunk = bid & 255;

    // Each thread owns l = l0..l0+3 for the whole loop (1024-float block
    // stride is a multiple of L=128, so the l-phase never changes).
    const int l0 = (tid & 31) * 4;

    float a0[4], a1[4], a2[4], a3[4];
#pragma unroll
    for (int j = 0; j < 4; ++j) {
        const int row = mask[m * L_DIM + l0 + j];     // 0..18
        const float4 e = *reinterpret_cast<const float4*>(eta_fault + row * 4);
        a0[j] = -e.x;   // -e0
        a1[j] = -e.y;   // -e1
        a2[j] = e.z;    //  e2
        a3[j] = e.w;    //  e3
    }

    const long long base = (long long)m * PER_M + (long long)chunk * PER_BLOCK + tid * 4;
    const float* zp = z + base;
    float*       op = out + base;

#pragma unroll 4
    for (int it = 0; it < ITERS; ++it) {
        const float4 zv = *reinterpret_cast<const float4*>(zp + it * (THREADS * 4));
        float4 ov;
        ov.x = __builtin_fmaf(a1[0], fast_tanh((zv.x - a2[0]) * a3[0]), a0[0]);
        ov.y = __builtin_fmaf(a1[1], fast_tanh((zv.y - a2[1]) * a3[1]), a0[1]);
        ov.z = __builtin_fmaf(a1[2], fast_tanh((zv.z - a2[2]) * a3[2]), a0[2]);
        ov.w = __builtin_fmaf(a1[3], fast_tanh((zv.w - a2[3]) * a3[3]), a0[3]);
        *reinterpret_cast<float4*>(op + it * (THREADS * 4)) = ov;
    }
}

extern "C" void kernel_launch(void* const* d_in, const int* in_sizes, int n_in,
                              void* d_out, int out_size, void* d_ws, size_t ws_size,
                              hipStream_t stream) {
    const float* z   = (const float*)d_in[0];
    const float* eta = (const float*)d_in[1];
    const int*   msk = (const int*)d_in[2];
    float*       out = (float*)d_out;

    dim3 grid(M_DIM * BLOCKS_PER_M);   // 2048 blocks
    dim3 block(THREADS);
    invrt_kernel<<<grid, block, 0, stream>>>(z, eta, msk, out);
}